// Round 7
// baseline (161.685 us; speedup 1.0000x reference)
//
#include <hip/hip_runtime.h>
#include <math.h>

#define N_ENTITY 200000
#define N_REL 32
#define DIM 64
#define N_HOP 2
#define N_MEM 32
#define BATCH 1024
#define PAIR_PER_HOP (BATCH * N_MEM)       // 32768
#define N_PAIR (N_HOP * PAIR_PER_HOP)      // 65536
#define CAP 3072                           // per-relation bucket capacity (mean 2048)
#define JBLK 32                            // blocks per relation in pairs kernel
#define WPB 4                              // waves per block
#define NBLK_PAIRS (JBLK * N_REL * WPB)    // 4096 per-wave reduction slots
#define TPAD 68                            // LDS transpose row pitch

typedef __attribute__((ext_vector_type(8))) short short8;   // 8 bf16 (A/B frag)
typedef __attribute__((ext_vector_type(4))) float floatx4;  // C/D frag

__device__ __forceinline__ float wave_reduce_sum(float v) {
    v += __shfl_xor(v, 1);
    v += __shfl_xor(v, 2);
    v += __shfl_xor(v, 4);
    v += __shfl_xor(v, 8);
    v += __shfl_xor(v, 16);
    v += __shfl_xor(v, 32);
    return v;
}

__device__ __forceinline__ unsigned short f2b(float x) {
    union { float f; unsigned u; } c; c.f = x;
    const unsigned r = (c.u + 0x7FFFu + ((c.u >> 16) & 1u)) >> 16;
    return (unsigned short)r;
}

__device__ __forceinline__ short8 pack8(const float4 a, const float4 b) {
    short8 s;
    s[0] = (short)f2b(a.x); s[1] = (short)f2b(a.y);
    s[2] = (short)f2b(a.z); s[3] = (short)f2b(a.w);
    s[4] = (short)f2b(b.x); s[5] = (short)f2b(b.y);
    s[6] = (short)f2b(b.z); s[7] = (short)f2b(b.w);
    return s;
}

__device__ __forceinline__ float sq4(const float4 a) {
    return a.x * a.x + a.y * a.y + a.z * a.z + a.w * a.w;
}

__device__ __forceinline__ float dot4(const float4 a, const float4 b) {
    return a.x * b.x + a.y * b.y + a.z * b.z + a.w * b.w;
}

// ---------------------------------------------------------------------------
// K0: bucket pair indices by relation (g_cnt zeroed by hipMemsetAsync first).
// ---------------------------------------------------------------------------
__global__ __launch_bounds__(256) void ripple_bin(
    const int* __restrict__ mr,
    int* __restrict__ g_cnt,     // [N_REL] (+done counter after it)
    int* __restrict__ list)      // [N_REL][CAP]
{
    __shared__ int hist[N_REL];
    __shared__ int cur[N_REL];
    const int tid = (int)threadIdx.x;
    const int pbase = (int)blockIdx.x * 1024;

    if (tid < N_REL) hist[tid] = 0;
    __syncthreads();

    int rv[4];
    #pragma unroll
    for (int u = 0; u < 4; ++u) {
        rv[u] = mr[pbase + u * 256 + tid];
        atomicAdd(&hist[rv[u]], 1);
    }
    __syncthreads();
    if (tid < N_REL) cur[tid] = atomicAdd(&g_cnt[tid], hist[tid]);
    __syncthreads();
    #pragma unroll
    for (int u = 0; u < 4; ++u) {
        const int r = rv[u];
        const int pos = atomicAdd(&cur[r], 1);
        if (pos < CAP) list[r * CAP + pos] = pbase + u * 256 + tid;
    }
}

// ---------------------------------------------------------------------------
// K1: MFMA gather-GEMM pairs kernel.
// Block-cooperative B staging: 256 threads pack R^T (bf16) into LDS once
// (+ exact fp32 ||R||^2 block reduction); each wave fills its 8 B-fragments
// with conflict-free ds_read_b128. Per 16-pair tile: A_h/A_t gathered in
// A-frag layout, 16 mfma -> Ch/Ct; single wave-private LDS transpose buffer
// (sequential Ct then Ch; DS ops are in-order per wave) turns C layout into
// row-major so lane m16 owns pair m16's full rows:
//   hRt = fp32 h regs . Ct row  -> KGE
//   v0 . Ch row -> hop0 logit (wsL);  Ch row -> wsRh (hop1), 4x b128
// ---------------------------------------------------------------------------
__global__ __launch_bounds__(256) void ripple_pairs(
    const int* __restrict__ items,
    const int* __restrict__ mh,
    const int* __restrict__ mt,
    const float* __restrict__ item_table,
    const float* __restrict__ rel_table,
    const int* __restrict__ g_cnt,
    const int* __restrict__ list,
    float* __restrict__ wsL,      // [PAIR_PER_HOP] hop0 logits
    float* __restrict__ wsRh,     // [PAIR_PER_HOP][DIM] hop1 Rh
    float* __restrict__ ws_kge,   // [NBLK_PAIRS]
    float* __restrict__ ws_l2)    // [NBLK_PAIRS]
{
    __shared__ __align__(16) float sTr[WPB][16 * TPAD];  // 17.4 KB transpose bufs
    __shared__ __align__(16) short8 sB[512];             // 8 KB packed bf16 R^T
    __shared__ float sRed[WPB];

    const int tid = (int)threadIdx.x;
    const int lane = tid & 63;
    const int w = tid >> 6;
    const int j = (int)blockIdx.x;
    const int r = (int)blockIdx.y;
    const int n = min(g_cnt[r], CAP);

    const int m16 = lane & 15;
    const int quad = lane >> 4;
    const int rb = r * CAP;
    const int wave_id = j * WPB + w;

    float* __restrict__ buf = &sTr[w][0];

    // ---- first-tile index chase, issued early (latency overlap) ----
    int tau = wave_id;
    int p = 0, hidx = 0, tidx = 0;
    if (tau * 16 < n) {
        const int pos = min(tau * 16 + m16, n - 1);
        p = list[rb + pos];              // same p across the 4 quads of m16
        hidx = mh[p];
        tidx = mt[p];
    }

    // ---- cooperative B staging: slot = s*256 + tn*64 + lane_s ----
    {
        const float* __restrict__ Rb = rel_table + (size_t)r * (DIM * DIM);
        float rsq = 0.f;
        #pragma unroll
        for (int u = 0; u < 2; ++u) {
            const int slot = tid + 256 * u;
            const int s = slot >> 8;
            const int tn = (slot >> 6) & 3;
            const int ls = slot & 63;
            const float* src = Rb + (size_t)(16 * tn + (ls & 15)) * DIM
                             + 32 * s + 8 * (ls >> 4);
            const float4 a = *(const float4*)src;
            const float4 b = *(const float4*)(src + 4);
            rsq += sq4(a) + sq4(b);
            sB[slot] = pack8(a, b);
        }
        rsq = wave_reduce_sum(rsq);
        if (lane == 0) sRed[w] = rsq;
    }
    __syncthreads();
    const float Rsum = sRed[0] + sRed[1] + sRed[2] + sRed[3];  // exact ||R||^2

    // ---- each wave's B fragments: 8 conflict-free ds_read_b128 ----
    short8 Bf[2][4];
    #pragma unroll
    for (int s = 0; s < 2; ++s)
        #pragma unroll
        for (int tn = 0; tn < 4; ++tn)
            Bf[s][tn] = sB[s * 256 + tn * 64 + lane];

    float kge = 0.f;
    float l2ht = 0.f;
    int cnt = 0;

    for (; tau * 16 < n; tau += JBLK * WPB) {
        const int base = tau * 16;
        const bool mvalid = (base + m16) < n;

        // ---- A rows (row = m16, cols 8q..8q+7 and 32+8q..+7) ----
        const float* __restrict__ hp = item_table + (size_t)hidx * DIM + 8 * quad;
        const float* __restrict__ tp = item_table + (size_t)tidx * DIM + 8 * quad;
        const float4 h0a = *(const float4*)hp;
        const float4 h0b = *(const float4*)(hp + 4);
        const float4 h1a = *(const float4*)(hp + 32);
        const float4 h1b = *(const float4*)(hp + 36);
        const float4 t0a = *(const float4*)tp;
        const float4 t0b = *(const float4*)(tp + 4);
        const float4 t1a = *(const float4*)(tp + 32);
        const float4 t1b = *(const float4*)(tp + 36);

        // ---- prefetch next tile's indices ----
        const int tau2 = tau + JBLK * WPB;
        int p2 = 0, h2 = 0, t2 = 0;
        if (tau2 * 16 < n) {
            const int pos2 = min(tau2 * 16 + m16, n - 1);
            p2 = list[rb + pos2];
            h2 = mh[p2];
            t2 = mt[p2];
        }

        if (mvalid) {
            l2ht += sq4(h0a) + sq4(h0b) + sq4(h1a) + sq4(h1b)
                  + sq4(t0a) + sq4(t0b) + sq4(t1a) + sq4(t1b);
        }

        const short8 Ah0 = pack8(h0a, h0b);
        const short8 Ah1 = pack8(h1a, h1b);
        const short8 At0 = pack8(t0a, t0b);
        const short8 At1 = pack8(t1a, t1b);

        floatx4 Ch[4], Ct[4];
        const floatx4 z4 = {0.f, 0.f, 0.f, 0.f};
        #pragma unroll
        for (int tn = 0; tn < 4; ++tn) {
            Ch[tn] = __builtin_amdgcn_mfma_f32_16x16x32_bf16(Ah0, Bf[0][tn], z4, 0, 0, 0);
            Ch[tn] = __builtin_amdgcn_mfma_f32_16x16x32_bf16(Ah1, Bf[1][tn], Ch[tn], 0, 0, 0);
            Ct[tn] = __builtin_amdgcn_mfma_f32_16x16x32_bf16(At0, Bf[0][tn], z4, 0, 0, 0);
            Ct[tn] = __builtin_amdgcn_mfma_f32_16x16x32_bf16(At1, Bf[1][tn], Ct[tn], 0, 0, 0);
        }

        // ---- Ct transpose: C layout (row=4*quad+q, col=m16+16tn) -> rows ----
        #pragma unroll
        for (int tn = 0; tn < 4; ++tn) {
            const int col = m16 + 16 * tn;
            #pragma unroll
            for (int q = 0; q < 4; ++q)
                buf[(4 * quad + q) * TPAD + col] = Ct[tn][q];
        }
        const float* rowT = buf + m16 * TPAD;
        const float4 ct0 = *(const float4*)(rowT + 8 * quad);
        const float4 ct1 = *(const float4*)(rowT + 8 * quad + 4);
        const float4 ct2 = *(const float4*)(rowT + 32 + 8 * quad);
        const float4 ct3 = *(const float4*)(rowT + 32 + 8 * quad + 4);
        float hrt = dot4(h0a, ct0) + dot4(h0b, ct1) + dot4(h1a, ct2) + dot4(h1b, ct3);
        hrt += __shfl_xor(hrt, 16);
        hrt += __shfl_xor(hrt, 32);

        // ---- Ch transpose (same buffer; DS in-order per wave) ----
        #pragma unroll
        for (int tn = 0; tn < 4; ++tn) {
            const int col = m16 + 16 * tn;
            #pragma unroll
            for (int q = 0; q < 4; ++q)
                buf[(4 * quad + q) * TPAD + col] = Ch[tn][q];
        }
        const float* rowC = buf + m16 * TPAD;
        const float4 c0 = *(const float4*)(rowC + 16 * quad);
        const float4 c1 = *(const float4*)(rowC + 16 * quad + 4);
        const float4 c2 = *(const float4*)(rowC + 16 * quad + 8);
        const float4 c3 = *(const float4*)(rowC + 16 * quad + 12);

        // ---- hop0 logit: v0 . Ch ----
        const bool hop0 = p < PAIR_PER_HOP;
        float lg = 0.f;
        if (hop0) {
            const float* __restrict__ vp =
                item_table + (size_t)items[p >> 5] * DIM + 16 * quad;
            lg = dot4(*(const float4*)vp, c0)
               + dot4(*(const float4*)(vp + 4), c1)
               + dot4(*(const float4*)(vp + 8), c2)
               + dot4(*(const float4*)(vp + 12), c3);
        }
        lg += __shfl_xor(lg, 16);
        lg += __shfl_xor(lg, 32);

        if (quad == 0 && mvalid) {
            kge += 1.f / (1.f + expf(-hrt));
            if (hop0) wsL[p] = lg;
        }

        // ---- hop1 Rh store: 4 x b128 ----
        if (mvalid && !hop0) {
            float* __restrict__ dst =
                wsRh + (size_t)(p - PAIR_PER_HOP) * DIM + 16 * quad;
            *(float4*)dst = c0;
            *(float4*)(dst + 4) = c1;
            *(float4*)(dst + 8) = c2;
            *(float4*)(dst + 12) = c3;
        }

        cnt += min(16, n - base);
        p = p2; hidx = h2; tidx = t2;
    }

    const float l2tot = wave_reduce_sum(l2ht) + (float)cnt * Rsum;
    const float kgetot = wave_reduce_sum(kge);
    if (lane == 0) {
        const int bid = (r * JBLK + j) * WPB + w;
        ws_kge[bid] = kgetot;
        ws_l2[bid] = l2tot;
    }
}

// ---------------------------------------------------------------------------
// K2: per-batch attention chain + fused last-block loss finalize.
// ---------------------------------------------------------------------------
__global__ __launch_bounds__(256) void ripple_attn(
    const int* __restrict__ items,
    const float* __restrict__ labels,
    const int* __restrict__ mt,
    const float* __restrict__ item_table,
    const float* __restrict__ W,
    const float* __restrict__ wsL,
    const float* __restrict__ wsRh,
    const float* __restrict__ ws_kge,
    const float* __restrict__ ws_l2,
    float* __restrict__ ws_bce,
    int* __restrict__ done_cnt,   // zeroed by memset each call
    float* __restrict__ out)
{
    __shared__ float sAtt[N_MEM];
    __shared__ __align__(16) float sO[4][DIM];
    __shared__ __align__(16) float sU[DIM];
    __shared__ __align__(16) float sV[DIM];
    __shared__ int sLast;
    __shared__ float sb[4], sk[4], sl[4];

    const int b = (int)blockIdx.x;
    const int tid = (int)threadIdx.x;
    const int lane = tid & 63;
    const int w = tid >> 6;

    float v_i = item_table[(size_t)items[b] * DIM + lane];
    float y_i = 0.f;

    for (int hop = 0; hop < N_HOP; ++hop) {
        if (hop == 0) {
            if (tid < N_MEM) sAtt[tid] = wsL[b * N_MEM + tid];
        } else {
            const int m = tid >> 3;
            const int d0 = (tid & 7) * 8;
            const float* __restrict__ rp =
                wsRh + (size_t)(b * N_MEM + m) * DIM + d0;
            const float4 ra = *(const float4*)rp;
            const float4 rb4 = *(const float4*)(rp + 4);
            const float4 va = *(const float4*)&sV[d0];
            const float4 vb = *(const float4*)&sV[d0 + 4];
            float dp = ra.x * va.x + ra.y * va.y + ra.z * va.z + ra.w * va.w
                     + rb4.x * vb.x + rb4.y * vb.y + rb4.z * vb.z + rb4.w * vb.w;
            dp += __shfl_xor(dp, 1);
            dp += __shfl_xor(dp, 2);
            dp += __shfl_xor(dp, 4);
            if ((tid & 7) == 0) sAtt[m] = dp;
        }
        __syncthreads();

        float mx = -1e30f;
        #pragma unroll
        for (int m = 0; m < N_MEM; ++m) mx = fmaxf(mx, sAtt[m]);
        float se = 0.f;
        float e_loc[8];
        #pragma unroll
        for (int m = 0; m < N_MEM; ++m) {
            const float e = expf(sAtt[m] - mx);
            se += e;
            if ((m >> 3) == w) e_loc[m & 7] = e;
        }
        const float inv = 1.f / se;

        float op = 0.f;
        #pragma unroll
        for (int q = 0; q < 8; ++q) {
            const int m = w * 8 + q;
            const int tidx = mt[hop * PAIR_PER_HOP + b * N_MEM + m];
            op = fmaf(item_table[(size_t)tidx * DIM + lane], e_loc[q] * inv, op);
        }
        sO[w][lane] = op;
        __syncthreads();

        const float o_i = sO[0][lane] + sO[1][lane] + sO[2][lane] + sO[3][lane];
        y_i += o_i;
        if (w == 0) sU[lane] = v_i + o_i;
        __syncthreads();

        const float4* __restrict__ Wrow = (const float4*)(W + (size_t)lane * DIM);
        float a0 = 0.f, a1 = 0.f, a2 = 0.f, a3 = 0.f;
        #pragma unroll
        for (int k = 0; k < 16; ++k) {
            const float4 w4 = Wrow[k];
            const float4 u4 = *(const float4*)&sU[k * 4];
            a0 = fmaf(w4.x, u4.x, a0);
            a1 = fmaf(w4.y, u4.y, a1);
            a2 = fmaf(w4.z, u4.z, a2);
            a3 = fmaf(w4.w, u4.w, a3);
        }
        v_i = (a0 + a1) + (a2 + a3);
        if (w == 0) sV[lane] = v_i;
        __syncthreads();
    }

    float s = wave_reduce_sum(v_i * y_i);
    s = 1.f / (1.f + expf(-s));
    if (tid == 0) {
        out[b] = s;
        const float lab = labels[b];
        const float logp = fmaxf(logf(s), -100.f);
        const float lognp = fmaxf(logf(1.f - s), -100.f);
        ws_bce[b] = lab * logp + (1.f - lab) * lognp;
        __threadfence();                       // publish ws_bce before count
        const int old = atomicAdd(done_cnt, 1);
        sLast = (old == BATCH - 1) ? 1 : 0;
    }
    __syncthreads();
    if (sLast == 0) return;

    // ---- last block: loss finalize ----
    float bsum = 0.f, ksum = 0.f, lsum = 0.f;
    for (int i = tid; i < BATCH; i += 256) bsum += ws_bce[i];
    for (int i = tid; i < NBLK_PAIRS; i += 256) {
        ksum += ws_kge[i];
        lsum += ws_l2[i];
    }
    bsum = wave_reduce_sum(bsum);
    ksum = wave_reduce_sum(ksum);
    lsum = wave_reduce_sum(lsum);
    if (lane == 0) { sb[w] = bsum; sk[w] = ksum; sl[w] = lsum; }
    __syncthreads();
    if (tid == 0) {
        const float bs = sb[0] + sb[1] + sb[2] + sb[3];
        const float ks = sk[0] + sk[1] + sk[2] + sk[3];
        const float ls = sl[0] + sl[1] + sl[2] + sl[3];
        const float base_loss = -bs / (float)BATCH;
        const float kge_loss = -0.01f * (ks / (float)(BATCH * N_MEM));
        const float l2_loss = 1e-7f * ls;
        out[BATCH + 0] = base_loss + kge_loss + l2_loss;
        out[BATCH + 1] = base_loss;
        out[BATCH + 2] = kge_loss;
        out[BATCH + 3] = l2_loss;
    }
}

extern "C" void kernel_launch(void* const* d_in, const int* in_sizes, int n_in,
                              void* d_out, int out_size, void* d_ws, size_t ws_size,
                              hipStream_t stream) {
    const int* items        = (const int*)d_in[0];
    const float* labels     = (const float*)d_in[1];
    const int* mh           = (const int*)d_in[2];
    const int* mr           = (const int*)d_in[3];
    const int* mt           = (const int*)d_in[4];
    const float* item_table = (const float*)d_in[5];
    const float* rel_table  = (const float*)d_in[6];
    const float* W          = (const float*)d_in[7];
    float* out = (float*)d_out;

    // workspace: wsL[32768] | wsRh[32768*64] | list[N_REL*CAP] |
    //            g_cnt[N_REL] + done_cnt[1] (contiguous, one memset) |
    //            ws_bce[BATCH] | ws_kge[NBLK_PAIRS] | ws_l2[NBLK_PAIRS]
    float* ws = (float*)d_ws;
    float* wsL    = ws;
    float* wsRh   = wsL + PAIR_PER_HOP;
    int*   list   = (int*)(wsRh + (size_t)PAIR_PER_HOP * DIM);
    int*   g_cnt  = list + N_REL * CAP;
    int*   done   = g_cnt + N_REL;
    float* ws_bce = (float*)(done + 1);
    float* ws_kge = ws_bce + BATCH;
    float* ws_l2  = ws_kge + NBLK_PAIRS;

    hipMemsetAsync(g_cnt, 0, (N_REL + 1) * sizeof(int), stream);
    ripple_bin<<<N_PAIR / 1024, 256, 0, stream>>>(mr, g_cnt, list);
    dim3 gpairs(JBLK, N_REL);
    ripple_pairs<<<gpairs, 256, 0, stream>>>(items, mh, mt, item_table, rel_table,
                                             g_cnt, list, wsL, wsRh, ws_kge, ws_l2);
    ripple_attn<<<BATCH, 256, 0, stream>>>(items, labels, mt, item_table, W,
                                           wsL, wsRh, ws_kge, ws_l2,
                                           ws_bce, done, out);
}

// Round 8
// 136.617 us; speedup vs baseline: 1.1835x; 1.1835x over previous
//
#include <hip/hip_runtime.h>
#include <math.h>

#define N_ENTITY 200000
#define N_REL 32
#define DIM 64
#define N_HOP 2
#define N_MEM 32
#define BATCH 1024
#define PAIR_PER_HOP (BATCH * N_MEM)       // 32768
#define N_PAIR (N_HOP * PAIR_PER_HOP)      // 65536
#define CAP 3072                           // per-relation bucket capacity (mean 2048)
#define JBLK 32                            // blocks per relation in pairs kernel
#define WPB 4                              // waves per block
#define NBLK_PAIRS (JBLK * N_REL * WPB)    // 4096 per-wave reduction slots
#define TPAD 68                            // LDS transpose row pitch

typedef __attribute__((ext_vector_type(8))) short short8;   // 8 bf16 (A/B frag)
typedef __attribute__((ext_vector_type(4))) float floatx4;  // C/D frag

__device__ __forceinline__ float wave_reduce_sum(float v) {
    v += __shfl_xor(v, 1);
    v += __shfl_xor(v, 2);
    v += __shfl_xor(v, 4);
    v += __shfl_xor(v, 8);
    v += __shfl_xor(v, 16);
    v += __shfl_xor(v, 32);
    return v;
}

__device__ __forceinline__ unsigned short f2b(float x) {
    union { float f; unsigned u; } c; c.f = x;
    const unsigned r = (c.u + 0x7FFFu + ((c.u >> 16) & 1u)) >> 16;
    return (unsigned short)r;
}

__device__ __forceinline__ short8 pack8(const float4 a, const float4 b) {
    short8 s;
    s[0] = (short)f2b(a.x); s[1] = (short)f2b(a.y);
    s[2] = (short)f2b(a.z); s[3] = (short)f2b(a.w);
    s[4] = (short)f2b(b.x); s[5] = (short)f2b(b.y);
    s[6] = (short)f2b(b.z); s[7] = (short)f2b(b.w);
    return s;
}

__device__ __forceinline__ float sq4(const float4 a) {
    return a.x * a.x + a.y * a.y + a.z * a.z + a.w * a.w;
}

__device__ __forceinline__ float dot4(const float4 a, const float4 b) {
    return a.x * b.x + a.y * b.y + a.z * b.z + a.w * b.w;
}

// ---------------------------------------------------------------------------
// K0: bucket pair indices by relation (g_cnt zeroed by hipMemsetAsync first).
// ---------------------------------------------------------------------------
__global__ __launch_bounds__(256) void ripple_bin(
    const int* __restrict__ mr,
    int* __restrict__ g_cnt,     // [N_REL]
    int* __restrict__ list)      // [N_REL][CAP]
{
    __shared__ int hist[N_REL];
    __shared__ int cur[N_REL];
    const int tid = (int)threadIdx.x;
    const int pbase = (int)blockIdx.x * 1024;

    if (tid < N_REL) hist[tid] = 0;
    __syncthreads();

    int rv[4];
    #pragma unroll
    for (int u = 0; u < 4; ++u) {
        rv[u] = mr[pbase + u * 256 + tid];
        atomicAdd(&hist[rv[u]], 1);
    }
    __syncthreads();
    if (tid < N_REL) cur[tid] = atomicAdd(&g_cnt[tid], hist[tid]);
    __syncthreads();
    #pragma unroll
    for (int u = 0; u < 4; ++u) {
        const int r = rv[u];
        const int pos = atomicAdd(&cur[r], 1);
        if (pos < CAP) list[r * CAP + pos] = pbase + u * 256 + tid;
    }
}

// ---------------------------------------------------------------------------
// K1: MFMA gather-GEMM pairs kernel (R7 structure: block-coop B staging).
// ---------------------------------------------------------------------------
__global__ __launch_bounds__(256) void ripple_pairs(
    const int* __restrict__ items,
    const int* __restrict__ mh,
    const int* __restrict__ mt,
    const float* __restrict__ item_table,
    const float* __restrict__ rel_table,
    const int* __restrict__ g_cnt,
    const int* __restrict__ list,
    float* __restrict__ wsL,      // [PAIR_PER_HOP] hop0 logits
    float* __restrict__ wsRh,     // [PAIR_PER_HOP][DIM] hop1 Rh
    float* __restrict__ ws_kge,   // [NBLK_PAIRS]
    float* __restrict__ ws_l2)    // [NBLK_PAIRS]
{
    __shared__ __align__(16) float sTr[WPB][16 * TPAD];  // 17.4 KB transpose bufs
    __shared__ __align__(16) short8 sB[512];             // 8 KB packed bf16 R^T
    __shared__ float sRed[WPB];

    const int tid = (int)threadIdx.x;
    const int lane = tid & 63;
    const int w = tid >> 6;
    const int j = (int)blockIdx.x;
    const int r = (int)blockIdx.y;
    const int n = min(g_cnt[r], CAP);

    const int m16 = lane & 15;
    const int quad = lane >> 4;
    const int rb = r * CAP;
    const int wave_id = j * WPB + w;

    float* __restrict__ buf = &sTr[w][0];

    // ---- first-tile index chase, issued early (latency overlap) ----
    int tau = wave_id;
    int p = 0, hidx = 0, tidx = 0;
    if (tau * 16 < n) {
        const int pos = min(tau * 16 + m16, n - 1);
        p = list[rb + pos];              // same p across the 4 quads of m16
        hidx = mh[p];
        tidx = mt[p];
    }

    // ---- cooperative B staging: slot = s*256 + tn*64 + lane_s ----
    {
        const float* __restrict__ Rb = rel_table + (size_t)r * (DIM * DIM);
        float rsq = 0.f;
        #pragma unroll
        for (int u = 0; u < 2; ++u) {
            const int slot = tid + 256 * u;
            const int s = slot >> 8;
            const int tn = (slot >> 6) & 3;
            const int ls = slot & 63;
            const float* src = Rb + (size_t)(16 * tn + (ls & 15)) * DIM
                             + 32 * s + 8 * (ls >> 4);
            const float4 a = *(const float4*)src;
            const float4 b = *(const float4*)(src + 4);
            rsq += sq4(a) + sq4(b);
            sB[slot] = pack8(a, b);
        }
        rsq = wave_reduce_sum(rsq);
        if (lane == 0) sRed[w] = rsq;
    }
    __syncthreads();
    const float Rsum = sRed[0] + sRed[1] + sRed[2] + sRed[3];  // exact ||R||^2

    // ---- each wave's B fragments: 8 conflict-free ds_read_b128 ----
    short8 Bf[2][4];
    #pragma unroll
    for (int s = 0; s < 2; ++s)
        #pragma unroll
        for (int tn = 0; tn < 4; ++tn)
            Bf[s][tn] = sB[s * 256 + tn * 64 + lane];

    float kge = 0.f;
    float l2ht = 0.f;
    int cnt = 0;

    for (; tau * 16 < n; tau += JBLK * WPB) {
        const int base = tau * 16;
        const bool mvalid = (base + m16) < n;

        // ---- A rows (row = m16, cols 8q..8q+7 and 32+8q..+7) ----
        const float* __restrict__ hp = item_table + (size_t)hidx * DIM + 8 * quad;
        const float* __restrict__ tp = item_table + (size_t)tidx * DIM + 8 * quad;
        const float4 h0a = *(const float4*)hp;
        const float4 h0b = *(const float4*)(hp + 4);
        const float4 h1a = *(const float4*)(hp + 32);
        const float4 h1b = *(const float4*)(hp + 36);
        const float4 t0a = *(const float4*)tp;
        const float4 t0b = *(const float4*)(tp + 4);
        const float4 t1a = *(const float4*)(tp + 32);
        const float4 t1b = *(const float4*)(tp + 36);

        // ---- prefetch next tile's indices ----
        const int tau2 = tau + JBLK * WPB;
        int p2 = 0, h2 = 0, t2 = 0;
        if (tau2 * 16 < n) {
            const int pos2 = min(tau2 * 16 + m16, n - 1);
            p2 = list[rb + pos2];
            h2 = mh[p2];
            t2 = mt[p2];
        }

        if (mvalid) {
            l2ht += sq4(h0a) + sq4(h0b) + sq4(h1a) + sq4(h1b)
                  + sq4(t0a) + sq4(t0b) + sq4(t1a) + sq4(t1b);
        }

        const short8 Ah0 = pack8(h0a, h0b);
        const short8 Ah1 = pack8(h1a, h1b);
        const short8 At0 = pack8(t0a, t0b);
        const short8 At1 = pack8(t1a, t1b);

        floatx4 Ch[4], Ct[4];
        const floatx4 z4 = {0.f, 0.f, 0.f, 0.f};
        #pragma unroll
        for (int tn = 0; tn < 4; ++tn) {
            Ch[tn] = __builtin_amdgcn_mfma_f32_16x16x32_bf16(Ah0, Bf[0][tn], z4, 0, 0, 0);
            Ch[tn] = __builtin_amdgcn_mfma_f32_16x16x32_bf16(Ah1, Bf[1][tn], Ch[tn], 0, 0, 0);
            Ct[tn] = __builtin_amdgcn_mfma_f32_16x16x32_bf16(At0, Bf[0][tn], z4, 0, 0, 0);
            Ct[tn] = __builtin_amdgcn_mfma_f32_16x16x32_bf16(At1, Bf[1][tn], Ct[tn], 0, 0, 0);
        }

        // ---- Ct transpose: C layout (row=4*quad+q, col=m16+16tn) -> rows ----
        #pragma unroll
        for (int tn = 0; tn < 4; ++tn) {
            const int col = m16 + 16 * tn;
            #pragma unroll
            for (int q = 0; q < 4; ++q)
                buf[(4 * quad + q) * TPAD + col] = Ct[tn][q];
        }
        const float* rowT = buf + m16 * TPAD;
        const float4 ct0 = *(const float4*)(rowT + 8 * quad);
        const float4 ct1 = *(const float4*)(rowT + 8 * quad + 4);
        const float4 ct2 = *(const float4*)(rowT + 32 + 8 * quad);
        const float4 ct3 = *(const float4*)(rowT + 32 + 8 * quad + 4);
        float hrt = dot4(h0a, ct0) + dot4(h0b, ct1) + dot4(h1a, ct2) + dot4(h1b, ct3);
        hrt += __shfl_xor(hrt, 16);
        hrt += __shfl_xor(hrt, 32);

        // ---- Ch transpose (same buffer; DS in-order per wave) ----
        #pragma unroll
        for (int tn = 0; tn < 4; ++tn) {
            const int col = m16 + 16 * tn;
            #pragma unroll
            for (int q = 0; q < 4; ++q)
                buf[(4 * quad + q) * TPAD + col] = Ch[tn][q];
        }
        const float* rowC = buf + m16 * TPAD;
        const float4 c0 = *(const float4*)(rowC + 16 * quad);
        const float4 c1 = *(const float4*)(rowC + 16 * quad + 4);
        const float4 c2 = *(const float4*)(rowC + 16 * quad + 8);
        const float4 c3 = *(const float4*)(rowC + 16 * quad + 12);

        // ---- hop0 logit: v0 . Ch ----
        const bool hop0 = p < PAIR_PER_HOP;
        float lg = 0.f;
        if (hop0) {
            const float* __restrict__ vp =
                item_table + (size_t)items[p >> 5] * DIM + 16 * quad;
            lg = dot4(*(const float4*)vp, c0)
               + dot4(*(const float4*)(vp + 4), c1)
               + dot4(*(const float4*)(vp + 8), c2)
               + dot4(*(const float4*)(vp + 12), c3);
        }
        lg += __shfl_xor(lg, 16);
        lg += __shfl_xor(lg, 32);

        if (quad == 0 && mvalid) {
            kge += 1.f / (1.f + expf(-hrt));
            if (hop0) wsL[p] = lg;
        }

        // ---- hop1 Rh store: 4 x b128 ----
        if (mvalid && !hop0) {
            float* __restrict__ dst =
                wsRh + (size_t)(p - PAIR_PER_HOP) * DIM + 16 * quad;
            *(float4*)dst = c0;
            *(float4*)(dst + 4) = c1;
            *(float4*)(dst + 8) = c2;
            *(float4*)(dst + 12) = c3;
        }

        cnt += min(16, n - base);
        p = p2; hidx = h2; tidx = t2;
    }

    const float l2tot = wave_reduce_sum(l2ht) + (float)cnt * Rsum;
    const float kgetot = wave_reduce_sum(kge);
    if (lane == 0) {
        const int bid = (r * JBLK + j) * WPB + w;
        ws_kge[bid] = kgetot;
        ws_l2[bid] = l2tot;
    }
}

// ---------------------------------------------------------------------------
// K2: per-batch attention chain, prefetch-restructured.
// ALL data-independent loads (v, hop0 logits, t-rows for both hops, wsRh
// fragments) are issued up front; the serial chain after that touches global
// memory only for the two W matvecs, done by wave 0 alone (was 4x redundant).
// ---------------------------------------------------------------------------
__global__ __launch_bounds__(256) void ripple_attn(
    const int* __restrict__ items,
    const float* __restrict__ labels,
    const int* __restrict__ mt,
    const float* __restrict__ item_table,
    const float* __restrict__ W,
    const float* __restrict__ wsL,
    const float* __restrict__ wsRh,
    float* __restrict__ out,
    float* __restrict__ ws_bce)
{
    __shared__ float sAtt[N_MEM];
    __shared__ __align__(16) float sO[4][DIM];
    __shared__ __align__(16) float sV[DIM];

    const int b = (int)blockIdx.x;
    const int tid = (int)threadIdx.x;
    const int lane = tid & 63;
    const int w = tid >> 6;

    // ================= upfront prefetch (no dependences) =================
    const float v0 = item_table[(size_t)items[b] * DIM + lane];

    float l0 = 0.f;
    if (tid < N_MEM) l0 = wsL[b * N_MEM + tid];

    // t rows, both hops: wave w owns slots w*8..w*8+7 (indices wave-uniform)
    float treg[2][8];
    #pragma unroll
    for (int hop = 0; hop < 2; ++hop)
        #pragma unroll
        for (int q = 0; q < 8; ++q) {
            const int tidx = mt[hop * PAIR_PER_HOP + b * N_MEM + w * 8 + q];
            treg[hop][q] = item_table[(size_t)tidx * DIM + lane];
        }

    // hop1 Rh fragment: thread handles slot m=tid>>3, dims (tid&7)*8..+8
    const int m1 = tid >> 3;
    const int d1 = (tid & 7) * 8;
    const float* __restrict__ rp = wsRh + (size_t)(b * N_MEM + m1) * DIM + d1;
    const float4 ra = *(const float4*)rp;
    const float4 rb4 = *(const float4*)(rp + 4);

    const float lab = labels[b];

    // ================= hop 0 =================
    if (tid < N_MEM) sAtt[tid] = l0;
    __syncthreads();

    float mx = -1e30f;
    #pragma unroll
    for (int m = 0; m < N_MEM; ++m) mx = fmaxf(mx, sAtt[m]);
    float se = 0.f;
    float e_loc[8];
    #pragma unroll
    for (int m = 0; m < N_MEM; ++m) {
        const float e = expf(sAtt[m] - mx);
        se += e;
        if ((m >> 3) == w) e_loc[m & 7] = e;
    }
    float inv = 1.f / se;

    float op = 0.f;
    #pragma unroll
    for (int q = 0; q < 8; ++q) op = fmaf(treg[0][q], e_loc[q] * inv, op);
    sO[w][lane] = op;
    __syncthreads();

    float y0 = 0.f, v1 = 0.f;
    if (w == 0) {
        const float o0 = sO[0][lane] + sO[1][lane] + sO[2][lane] + sO[3][lane];
        y0 = o0;
        // v1 = W (v0 + o0): wave0 only, u broadcast via shuffle-free LDS? ->
        // u lives per-lane; do matvec with u from LDS sV staging
        sV[lane] = v0 + o0;            // stage u (wave-coherent for wave 0)
        const float4* __restrict__ Wrow = (const float4*)(W + (size_t)lane * DIM);
        float a0 = 0.f, a1 = 0.f, a2 = 0.f, a3 = 0.f;
        #pragma unroll
        for (int k = 0; k < 16; ++k) {
            const float4 w4 = Wrow[k];
            const float4 u4 = *(const float4*)&sV[k * 4];
            a0 = fmaf(w4.x, u4.x, a0);
            a1 = fmaf(w4.y, u4.y, a1);
            a2 = fmaf(w4.z, u4.z, a2);
            a3 = fmaf(w4.w, u4.w, a3);
        }
        v1 = (a0 + a1) + (a2 + a3);
        sV[lane] = v1;                 // publish v1 (in-order DS per wave)
    }
    __syncthreads();

    // ================= hop 1 =================
    // logits: 8 threads per slot, prefetched ra/rb4 . v1
    {
        const float4 va = *(const float4*)&sV[d1];
        const float4 vb = *(const float4*)&sV[d1 + 4];
        float dp = dot4(ra, va) + dot4(rb4, vb);
        dp += __shfl_xor(dp, 1);
        dp += __shfl_xor(dp, 2);
        dp += __shfl_xor(dp, 4);
        if ((tid & 7) == 0) sAtt[m1] = dp;
    }
    __syncthreads();

    mx = -1e30f;
    #pragma unroll
    for (int m = 0; m < N_MEM; ++m) mx = fmaxf(mx, sAtt[m]);
    se = 0.f;
    #pragma unroll
    for (int m = 0; m < N_MEM; ++m) {
        const float e = expf(sAtt[m] - mx);
        se += e;
        if ((m >> 3) == w) e_loc[m & 7] = e;
    }
    inv = 1.f / se;

    op = 0.f;
    #pragma unroll
    for (int q = 0; q < 8; ++q) op = fmaf(treg[1][q], e_loc[q] * inv, op);
    sO[w][lane] = op;
    __syncthreads();

    if (w != 0) return;   // waves 1-3 done (past their last barrier)

    // ================= wave-0 epilogue =================
    const float o1 = sO[0][lane] + sO[1][lane] + sO[2][lane] + sO[3][lane];
    const float y = y0 + o1;
    sV[lane] = v1 + o1;               // u1 (wave-coherent)
    const float4* __restrict__ Wrow = (const float4*)(W + (size_t)lane * DIM);
    float a0 = 0.f, a1 = 0.f, a2 = 0.f, a3 = 0.f;
    #pragma unroll
    for (int k = 0; k < 16; ++k) {
        const float4 w4 = Wrow[k];
        const float4 u4 = *(const float4*)&sV[k * 4];
        a0 = fmaf(w4.x, u4.x, a0);
        a1 = fmaf(w4.y, u4.y, a1);
        a2 = fmaf(w4.z, u4.z, a2);
        a3 = fmaf(w4.w, u4.w, a3);
    }
    const float v2 = (a0 + a1) + (a2 + a3);

    float s = wave_reduce_sum(v2 * y);
    s = 1.f / (1.f + expf(-s));
    if (lane == 0) {
        out[b] = s;
        const float logp = fmaxf(logf(s), -100.f);
        const float lognp = fmaxf(logf(1.f - s), -100.f);
        ws_bce[b] = lab * logp + (1.f - lab) * lognp;
    }
}

// ---------------------------------------------------------------------------
// K3: loss finalize (separate kernel again — no device fences in attn).
// ---------------------------------------------------------------------------
__global__ __launch_bounds__(256) void ripple_finalize(
    const float* __restrict__ ws_bce,
    const float* __restrict__ ws_kge,
    const float* __restrict__ ws_l2,
    float* __restrict__ out)
{
    __shared__ float sb[4], sk[4], sl[4];
    const int tid = (int)threadIdx.x;
    float bsum = 0.f, ksum = 0.f, lsum = 0.f;
    for (int i = tid; i < BATCH; i += 256) bsum += ws_bce[i];
    for (int i = tid; i < NBLK_PAIRS; i += 256) {
        ksum += ws_kge[i];
        lsum += ws_l2[i];
    }
    bsum = wave_reduce_sum(bsum);
    ksum = wave_reduce_sum(ksum);
    lsum = wave_reduce_sum(lsum);
    const int w = tid >> 6;
    if ((tid & 63) == 0) { sb[w] = bsum; sk[w] = ksum; sl[w] = lsum; }
    __syncthreads();
    if (tid == 0) {
        const float bs = sb[0] + sb[1] + sb[2] + sb[3];
        const float ks = sk[0] + sk[1] + sk[2] + sk[3];
        const float ls = sl[0] + sl[1] + sl[2] + sl[3];
        const float base_loss = -bs / (float)BATCH;
        const float kge_loss = -0.01f * (ks / (float)(BATCH * N_MEM));
        const float l2_loss = 1e-7f * ls;
        out[BATCH + 0] = base_loss + kge_loss + l2_loss;
        out[BATCH + 1] = base_loss;
        out[BATCH + 2] = kge_loss;
        out[BATCH + 3] = l2_loss;
    }
}

extern "C" void kernel_launch(void* const* d_in, const int* in_sizes, int n_in,
                              void* d_out, int out_size, void* d_ws, size_t ws_size,
                              hipStream_t stream) {
    const int* items        = (const int*)d_in[0];
    const float* labels     = (const float*)d_in[1];
    const int* mh           = (const int*)d_in[2];
    const int* mr           = (const int*)d_in[3];
    const int* mt           = (const int*)d_in[4];
    const float* item_table = (const float*)d_in[5];
    const float* rel_table  = (const float*)d_in[6];
    const float* W          = (const float*)d_in[7];
    float* out = (float*)d_out;

    // workspace: wsL[32768] | wsRh[32768*64] | list[N_REL*CAP] | g_cnt[N_REL]
    //            | ws_bce[BATCH] | ws_kge[NBLK_PAIRS] | ws_l2[NBLK_PAIRS]
    float* ws = (float*)d_ws;
    float* wsL    = ws;
    float* wsRh   = wsL + PAIR_PER_HOP;
    int*   list   = (int*)(wsRh + (size_t)PAIR_PER_HOP * DIM);
    int*   g_cnt  = list + N_REL * CAP;
    float* ws_bce = (float*)(g_cnt + N_REL);
    float* ws_kge = ws_bce + BATCH;
    float* ws_l2  = ws_kge + NBLK_PAIRS;

    hipMemsetAsync(g_cnt, 0, N_REL * sizeof(int), stream);
    ripple_bin<<<N_PAIR / 1024, 256, 0, stream>>>(mr, g_cnt, list);
    dim3 gpairs(JBLK, N_REL);
    ripple_pairs<<<gpairs, 256, 0, stream>>>(items, mh, mt, item_table, rel_table,
                                             g_cnt, list, wsL, wsRh, ws_kge, ws_l2);
    ripple_attn<<<BATCH, 256, 0, stream>>>(items, labels, mt, item_table, W,
                                           wsL, wsRh, out, ws_bce);
    ripple_finalize<<<1, 256, 0, stream>>>(ws_bce, ws_kge, ws_l2, out);
}

// Round 9
// 132.982 us; speedup vs baseline: 1.2158x; 1.0273x over previous
//
#include <hip/hip_runtime.h>
#include <math.h>

#define N_ENTITY 200000
#define N_REL 32
#define DIM 64
#define N_HOP 2
#define N_MEM 32
#define BATCH 1024
#define PAIR_PER_HOP (BATCH * N_MEM)       // 32768
#define N_PAIR (N_HOP * PAIR_PER_HOP)      // 65536
#define CAP 3072                           // per-relation bucket capacity (mean 2048)
#define JBLK 32                            // blocks per relation in pairs kernel
#define WPB 4                              // waves per block
#define NBLK_PAIRS (JBLK * N_REL * WPB)    // 4096 per-wave reduction slots
#define TPAD 68                            // LDS transpose row pitch

typedef __attribute__((ext_vector_type(8))) short short8;   // 8 bf16 (A/B frag)
typedef __attribute__((ext_vector_type(4))) float floatx4;  // C/D frag

__device__ __forceinline__ float wave_reduce_sum(float v) {
    v += __shfl_xor(v, 1);
    v += __shfl_xor(v, 2);
    v += __shfl_xor(v, 4);
    v += __shfl_xor(v, 8);
    v += __shfl_xor(v, 16);
    v += __shfl_xor(v, 32);
    return v;
}

__device__ __forceinline__ unsigned short f2b(float x) {
    union { float f; unsigned u; } c; c.f = x;
    const unsigned r = (c.u + 0x7FFFu + ((c.u >> 16) & 1u)) >> 16;
    return (unsigned short)r;
}

__device__ __forceinline__ float b2f(short s) {
    union { unsigned u; float f; } c;
    c.u = ((unsigned)(unsigned short)s) << 16;
    return c.f;
}

__device__ __forceinline__ short8 pack8(const float4 a, const float4 b) {
    short8 s;
    s[0] = (short)f2b(a.x); s[1] = (short)f2b(a.y);
    s[2] = (short)f2b(a.z); s[3] = (short)f2b(a.w);
    s[4] = (short)f2b(b.x); s[5] = (short)f2b(b.y);
    s[6] = (short)f2b(b.z); s[7] = (short)f2b(b.w);
    return s;
}

__device__ __forceinline__ float sq4(const float4 a) {
    return a.x * a.x + a.y * a.y + a.z * a.z + a.w * a.w;
}

__device__ __forceinline__ float dot4(const float4 a, const float4 b) {
    return a.x * b.x + a.y * b.y + a.z * b.z + a.w * b.w;
}

// ---------------------------------------------------------------------------
// K0: bucket pair indices by relation (g_cnt zeroed by hipMemsetAsync first).
// ---------------------------------------------------------------------------
__global__ __launch_bounds__(256) void ripple_bin(
    const int* __restrict__ mr,
    int* __restrict__ g_cnt,     // [N_REL]
    int* __restrict__ list)      // [N_REL][CAP]
{
    __shared__ int hist[N_REL];
    __shared__ int cur[N_REL];
    const int tid = (int)threadIdx.x;
    const int pbase = (int)blockIdx.x * 1024;

    if (tid < N_REL) hist[tid] = 0;
    __syncthreads();

    int rv[4];
    #pragma unroll
    for (int u = 0; u < 4; ++u) {
        rv[u] = mr[pbase + u * 256 + tid];
        atomicAdd(&hist[rv[u]], 1);
    }
    __syncthreads();
    if (tid < N_REL) cur[tid] = atomicAdd(&g_cnt[tid], hist[tid]);
    __syncthreads();
    #pragma unroll
    for (int u = 0; u < 4; ++u) {
        const int r = rv[u];
        const int pos = atomicAdd(&cur[r], 1);
        if (pos < CAP) list[r * CAP + pos] = pbase + u * 256 + tid;
    }
}

// ---------------------------------------------------------------------------
// K1: MFMA gather-GEMM pairs kernel.
// R9: v0 chase hoisted to the top of the tile loop (overlaps A gathers);
// next-tile iidx prefetched with p2/h2/t2; wsRh stored in bf16 (short8 x2).
// ---------------------------------------------------------------------------
__global__ __launch_bounds__(256) void ripple_pairs(
    const int* __restrict__ items,
    const int* __restrict__ mh,
    const int* __restrict__ mt,
    const float* __restrict__ item_table,
    const float* __restrict__ rel_table,
    const int* __restrict__ g_cnt,
    const int* __restrict__ list,
    float* __restrict__ wsL,            // [PAIR_PER_HOP] hop0 logits
    unsigned short* __restrict__ wsRh,  // [PAIR_PER_HOP][DIM] hop1 Rh (bf16)
    float* __restrict__ ws_kge,         // [NBLK_PAIRS]
    float* __restrict__ ws_l2)          // [NBLK_PAIRS]
{
    __shared__ __align__(16) float sTr[WPB][16 * TPAD];  // 17.4 KB transpose bufs
    __shared__ __align__(16) short8 sB[512];             // 8 KB packed bf16 R^T
    __shared__ float sRed[WPB];

    const int tid = (int)threadIdx.x;
    const int lane = tid & 63;
    const int w = tid >> 6;
    const int j = (int)blockIdx.x;
    const int r = (int)blockIdx.y;
    const int n = min(g_cnt[r], CAP);

    const int m16 = lane & 15;
    const int quad = lane >> 4;
    const int rb = r * CAP;
    const int wave_id = j * WPB + w;

    float* __restrict__ buf = &sTr[w][0];

    // ---- first-tile index chase, issued early (latency overlap) ----
    int tau = wave_id;
    int p = 0, hidx = 0, tidx = 0, iidx = 0;
    if (tau * 16 < n) {
        const int pos = min(tau * 16 + m16, n - 1);
        p = list[rb + pos];              // same p across the 4 quads of m16
        hidx = mh[p];
        tidx = mt[p];
        iidx = (p < PAIR_PER_HOP) ? items[p >> 5] : 0;
    }

    // ---- cooperative B staging: slot = s*256 + tn*64 + lane_s ----
    {
        const float* __restrict__ Rb = rel_table + (size_t)r * (DIM * DIM);
        float rsq = 0.f;
        #pragma unroll
        for (int u = 0; u < 2; ++u) {
            const int slot = tid + 256 * u;
            const int s = slot >> 8;
            const int tn = (slot >> 6) & 3;
            const int ls = slot & 63;
            const float* src = Rb + (size_t)(16 * tn + (ls & 15)) * DIM
                             + 32 * s + 8 * (ls >> 4);
            const float4 a = *(const float4*)src;
            const float4 b = *(const float4*)(src + 4);
            rsq += sq4(a) + sq4(b);
            sB[slot] = pack8(a, b);
        }
        rsq = wave_reduce_sum(rsq);
        if (lane == 0) sRed[w] = rsq;
    }
    __syncthreads();
    const float Rsum = sRed[0] + sRed[1] + sRed[2] + sRed[3];  // exact ||R||^2

    // ---- each wave's B fragments: 8 conflict-free ds_read_b128 ----
    short8 Bf[2][4];
    #pragma unroll
    for (int s = 0; s < 2; ++s)
        #pragma unroll
        for (int tn = 0; tn < 4; ++tn)
            Bf[s][tn] = sB[s * 256 + tn * 64 + lane];

    float kge = 0.f;
    float l2ht = 0.f;
    int cnt = 0;

    for (; tau * 16 < n; tau += JBLK * WPB) {
        const int base = tau * 16;
        const bool mvalid = (base + m16) < n;
        const bool hop0 = p < PAIR_PER_HOP;

        // ---- A rows + hoisted v0 row, all issued together ----
        const float* __restrict__ hp = item_table + (size_t)hidx * DIM + 8 * quad;
        const float* __restrict__ tp = item_table + (size_t)tidx * DIM + 8 * quad;
        const float4 h0a = *(const float4*)hp;
        const float4 h0b = *(const float4*)(hp + 4);
        const float4 h1a = *(const float4*)(hp + 32);
        const float4 h1b = *(const float4*)(hp + 36);
        const float4 t0a = *(const float4*)tp;
        const float4 t0b = *(const float4*)(tp + 4);
        const float4 t1a = *(const float4*)(tp + 32);
        const float4 t1b = *(const float4*)(tp + 36);

        float4 va0, va1, va2, va3;
        va0 = va1 = va2 = va3 = make_float4(0.f, 0.f, 0.f, 0.f);
        if (hop0) {
            const float* __restrict__ vp =
                item_table + (size_t)iidx * DIM + 16 * quad;
            va0 = *(const float4*)vp;
            va1 = *(const float4*)(vp + 4);
            va2 = *(const float4*)(vp + 8);
            va3 = *(const float4*)(vp + 12);
        }

        // ---- prefetch next tile's indices ----
        const int tau2 = tau + JBLK * WPB;
        int p2 = 0, h2 = 0, t2 = 0, i2 = 0;
        if (tau2 * 16 < n) {
            const int pos2 = min(tau2 * 16 + m16, n - 1);
            p2 = list[rb + pos2];
            h2 = mh[p2];
            t2 = mt[p2];
            i2 = (p2 < PAIR_PER_HOP) ? items[p2 >> 5] : 0;
        }

        if (mvalid) {
            l2ht += sq4(h0a) + sq4(h0b) + sq4(h1a) + sq4(h1b)
                  + sq4(t0a) + sq4(t0b) + sq4(t1a) + sq4(t1b);
        }

        const short8 Ah0 = pack8(h0a, h0b);
        const short8 Ah1 = pack8(h1a, h1b);
        const short8 At0 = pack8(t0a, t0b);
        const short8 At1 = pack8(t1a, t1b);

        floatx4 Ch[4], Ct[4];
        const floatx4 z4 = {0.f, 0.f, 0.f, 0.f};
        #pragma unroll
        for (int tn = 0; tn < 4; ++tn) {
            Ch[tn] = __builtin_amdgcn_mfma_f32_16x16x32_bf16(Ah0, Bf[0][tn], z4, 0, 0, 0);
            Ch[tn] = __builtin_amdgcn_mfma_f32_16x16x32_bf16(Ah1, Bf[1][tn], Ch[tn], 0, 0, 0);
            Ct[tn] = __builtin_amdgcn_mfma_f32_16x16x32_bf16(At0, Bf[0][tn], z4, 0, 0, 0);
            Ct[tn] = __builtin_amdgcn_mfma_f32_16x16x32_bf16(At1, Bf[1][tn], Ct[tn], 0, 0, 0);
        }

        // ---- Ct transpose: C layout (row=4*quad+q, col=m16+16tn) -> rows ----
        #pragma unroll
        for (int tn = 0; tn < 4; ++tn) {
            const int col = m16 + 16 * tn;
            #pragma unroll
            for (int q = 0; q < 4; ++q)
                buf[(4 * quad + q) * TPAD + col] = Ct[tn][q];
        }
        const float* rowT = buf + m16 * TPAD;
        const float4 ct0 = *(const float4*)(rowT + 8 * quad);
        const float4 ct1 = *(const float4*)(rowT + 8 * quad + 4);
        const float4 ct2 = *(const float4*)(rowT + 32 + 8 * quad);
        const float4 ct3 = *(const float4*)(rowT + 32 + 8 * quad + 4);
        float hrt = dot4(h0a, ct0) + dot4(h0b, ct1) + dot4(h1a, ct2) + dot4(h1b, ct3);
        hrt += __shfl_xor(hrt, 16);
        hrt += __shfl_xor(hrt, 32);

        // ---- Ch transpose (same buffer; DS in-order per wave) ----
        #pragma unroll
        for (int tn = 0; tn < 4; ++tn) {
            const int col = m16 + 16 * tn;
            #pragma unroll
            for (int q = 0; q < 4; ++q)
                buf[(4 * quad + q) * TPAD + col] = Ch[tn][q];
        }
        const float* rowC = buf + m16 * TPAD;
        const float4 c0 = *(const float4*)(rowC + 16 * quad);
        const float4 c1 = *(const float4*)(rowC + 16 * quad + 4);
        const float4 c2 = *(const float4*)(rowC + 16 * quad + 8);
        const float4 c3 = *(const float4*)(rowC + 16 * quad + 12);

        // ---- hop0 logit: prefetched v0 regs . Ch ----
        float lg = dot4(va0, c0) + dot4(va1, c1) + dot4(va2, c2) + dot4(va3, c3);
        lg += __shfl_xor(lg, 16);
        lg += __shfl_xor(lg, 32);

        if (quad == 0 && mvalid) {
            kge += 1.f / (1.f + expf(-hrt));
            if (hop0) wsL[p] = lg;
        }

        // ---- hop1 Rh store: bf16, 2 x 16B ----
        if (mvalid && !hop0) {
            unsigned short* __restrict__ dst =
                wsRh + (size_t)(p - PAIR_PER_HOP) * DIM + 16 * quad;
            *(short8*)dst = pack8(c0, c1);
            *(short8*)(dst + 8) = pack8(c2, c3);
        }

        cnt += min(16, n - base);
        p = p2; hidx = h2; tidx = t2; iidx = i2;
    }

    const float l2tot = wave_reduce_sum(l2ht) + (float)cnt * Rsum;
    const float kgetot = wave_reduce_sum(kge);
    if (lane == 0) {
        const int bid = (r * JBLK + j) * WPB + w;
        ws_kge[bid] = kgetot;
        ws_l2[bid] = l2tot;
    }
}

// ---------------------------------------------------------------------------
// K2: per-batch attention chain (R8 structure; wsRh now bf16).
// ---------------------------------------------------------------------------
__global__ __launch_bounds__(256) void ripple_attn(
    const int* __restrict__ items,
    const float* __restrict__ labels,
    const int* __restrict__ mt,
    const float* __restrict__ item_table,
    const float* __restrict__ W,
    const float* __restrict__ wsL,
    const unsigned short* __restrict__ wsRh,
    float* __restrict__ out,
    float* __restrict__ ws_bce)
{
    __shared__ float sAtt[N_MEM];
    __shared__ __align__(16) float sO[4][DIM];
    __shared__ __align__(16) float sV[DIM];

    const int b = (int)blockIdx.x;
    const int tid = (int)threadIdx.x;
    const int lane = tid & 63;
    const int w = tid >> 6;

    // ================= upfront prefetch (no dependences) =================
    const float v0 = item_table[(size_t)items[b] * DIM + lane];

    float l0 = 0.f;
    if (tid < N_MEM) l0 = wsL[b * N_MEM + tid];

    // t rows, both hops: wave w owns slots w*8..w*8+7 (indices wave-uniform)
    float treg[2][8];
    #pragma unroll
    for (int hop = 0; hop < 2; ++hop)
        #pragma unroll
        for (int q = 0; q < 8; ++q) {
            const int tidx = mt[hop * PAIR_PER_HOP + b * N_MEM + w * 8 + q];
            treg[hop][q] = item_table[(size_t)tidx * DIM + lane];
        }

    // hop1 Rh fragment: thread handles slot m=tid>>3, dims (tid&7)*8..+8 (bf16)
    const int m1 = tid >> 3;
    const int d1 = (tid & 7) * 8;
    const short8 rv8 =
        *(const short8*)(wsRh + (size_t)(b * N_MEM + m1) * DIM + d1);

    const float lab = labels[b];

    // ================= hop 0 =================
    if (tid < N_MEM) sAtt[tid] = l0;
    __syncthreads();

    float mx = -1e30f;
    #pragma unroll
    for (int m = 0; m < N_MEM; ++m) mx = fmaxf(mx, sAtt[m]);
    float se = 0.f;
    float e_loc[8];
    #pragma unroll
    for (int m = 0; m < N_MEM; ++m) {
        const float e = expf(sAtt[m] - mx);
        se += e;
        if ((m >> 3) == w) e_loc[m & 7] = e;
    }
    float inv = 1.f / se;

    float op = 0.f;
    #pragma unroll
    for (int q = 0; q < 8; ++q) op = fmaf(treg[0][q], e_loc[q] * inv, op);
    sO[w][lane] = op;
    __syncthreads();

    float y0 = 0.f, v1 = 0.f;
    if (w == 0) {
        const float o0 = sO[0][lane] + sO[1][lane] + sO[2][lane] + sO[3][lane];
        y0 = o0;
        sV[lane] = v0 + o0;            // stage u (wave-coherent for wave 0)
        const float4* __restrict__ Wrow = (const float4*)(W + (size_t)lane * DIM);
        float a0 = 0.f, a1 = 0.f, a2 = 0.f, a3 = 0.f;
        #pragma unroll
        for (int k = 0; k < 16; ++k) {
            const float4 w4 = Wrow[k];
            const float4 u4 = *(const float4*)&sV[k * 4];
            a0 = fmaf(w4.x, u4.x, a0);
            a1 = fmaf(w4.y, u4.y, a1);
            a2 = fmaf(w4.z, u4.z, a2);
            a3 = fmaf(w4.w, u4.w, a3);
        }
        v1 = (a0 + a1) + (a2 + a3);
        sV[lane] = v1;                 // publish v1 (in-order DS per wave)
    }
    __syncthreads();

    // ================= hop 1 =================
    {
        float dp = 0.f;
        #pragma unroll
        for (int e = 0; e < 8; ++e) dp = fmaf(b2f(rv8[e]), sV[d1 + e], dp);
        dp += __shfl_xor(dp, 1);
        dp += __shfl_xor(dp, 2);
        dp += __shfl_xor(dp, 4);
        if ((tid & 7) == 0) sAtt[m1] = dp;
    }
    __syncthreads();

    mx = -1e30f;
    #pragma unroll
    for (int m = 0; m < N_MEM; ++m) mx = fmaxf(mx, sAtt[m]);
    se = 0.f;
    #pragma unroll
    for (int m = 0; m < N_MEM; ++m) {
        const float e = expf(sAtt[m] - mx);
        se += e;
        if ((m >> 3) == w) e_loc[m & 7] = e;
    }
    inv = 1.f / se;

    op = 0.f;
    #pragma unroll
    for (int q = 0; q < 8; ++q) op = fmaf(treg[1][q], e_loc[q] * inv, op);
    sO[w][lane] = op;
    __syncthreads();

    if (w != 0) return;   // waves 1-3 done (past their last barrier)

    // ================= wave-0 epilogue =================
    const float o1 = sO[0][lane] + sO[1][lane] + sO[2][lane] + sO[3][lane];
    const float y = y0 + o1;
    sV[lane] = v1 + o1;               // u1 (wave-coherent)
    const float4* __restrict__ Wrow = (const float4*)(W + (size_t)lane * DIM);
    float a0 = 0.f, a1 = 0.f, a2 = 0.f, a3 = 0.f;
    #pragma unroll
    for (int k = 0; k < 16; ++k) {
        const float4 w4 = Wrow[k];
        const float4 u4 = *(const float4*)&sV[k * 4];
        a0 = fmaf(w4.x, u4.x, a0);
        a1 = fmaf(w4.y, u4.y, a1);
        a2 = fmaf(w4.z, u4.z, a2);
        a3 = fmaf(w4.w, u4.w, a3);
    }
    const float v2 = (a0 + a1) + (a2 + a3);

    float s = wave_reduce_sum(v2 * y);
    s = 1.f / (1.f + expf(-s));
    if (lane == 0) {
        out[b] = s;
        const float logp = fmaxf(logf(s), -100.f);
        const float lognp = fmaxf(logf(1.f - s), -100.f);
        ws_bce[b] = lab * logp + (1.f - lab) * lognp;
    }
}

// ---------------------------------------------------------------------------
// K3: loss finalize.
// ---------------------------------------------------------------------------
__global__ __launch_bounds__(256) void ripple_finalize(
    const float* __restrict__ ws_bce,
    const float* __restrict__ ws_kge,
    const float* __restrict__ ws_l2,
    float* __restrict__ out)
{
    __shared__ float sb[4], sk[4], sl[4];
    const int tid = (int)threadIdx.x;
    float bsum = 0.f, ksum = 0.f, lsum = 0.f;
    for (int i = tid; i < BATCH; i += 256) bsum += ws_bce[i];
    for (int i = tid; i < NBLK_PAIRS; i += 256) {
        ksum += ws_kge[i];
        lsum += ws_l2[i];
    }
    bsum = wave_reduce_sum(bsum);
    ksum = wave_reduce_sum(ksum);
    lsum = wave_reduce_sum(lsum);
    const int w = tid >> 6;
    if ((tid & 63) == 0) { sb[w] = bsum; sk[w] = ksum; sl[w] = lsum; }
    __syncthreads();
    if (tid == 0) {
        const float bs = sb[0] + sb[1] + sb[2] + sb[3];
        const float ks = sk[0] + sk[1] + sk[2] + sk[3];
        const float ls = sl[0] + sl[1] + sl[2] + sl[3];
        const float base_loss = -bs / (float)BATCH;
        const float kge_loss = -0.01f * (ks / (float)(BATCH * N_MEM));
        const float l2_loss = 1e-7f * ls;
        out[BATCH + 0] = base_loss + kge_loss + l2_loss;
        out[BATCH + 1] = base_loss;
        out[BATCH + 2] = kge_loss;
        out[BATCH + 3] = l2_loss;
    }
}

extern "C" void kernel_launch(void* const* d_in, const int* in_sizes, int n_in,
                              void* d_out, int out_size, void* d_ws, size_t ws_size,
                              hipStream_t stream) {
    const int* items        = (const int*)d_in[0];
    const float* labels     = (const float*)d_in[1];
    const int* mh           = (const int*)d_in[2];
    const int* mr           = (const int*)d_in[3];
    const int* mt           = (const int*)d_in[4];
    const float* item_table = (const float*)d_in[5];
    const float* rel_table  = (const float*)d_in[6];
    const float* W          = (const float*)d_in[7];
    float* out = (float*)d_out;

    // workspace: wsL[32768] f32 | wsRh[32768*64] bf16 (4.2MB) |
    //            list[N_REL*CAP] int | g_cnt[N_REL] |
    //            ws_bce[BATCH] | ws_kge[NBLK_PAIRS] | ws_l2[NBLK_PAIRS]
    float* ws = (float*)d_ws;
    float* wsL            = ws;
    unsigned short* wsRh  = (unsigned short*)(wsL + PAIR_PER_HOP);
    int*   list           = (int*)(wsRh + (size_t)PAIR_PER_HOP * DIM);
    int*   g_cnt          = list + N_REL * CAP;
    float* ws_bce         = (float*)(g_cnt + N_REL);
    float* ws_kge         = ws_bce + BATCH;
    float* ws_l2          = ws_kge + NBLK_PAIRS;

    hipMemsetAsync(g_cnt, 0, N_REL * sizeof(int), stream);
    ripple_bin<<<N_PAIR / 1024, 256, 0, stream>>>(mr, g_cnt, list);
    dim3 gpairs(JBLK, N_REL);
    ripple_pairs<<<gpairs, 256, 0, stream>>>(items, mh, mt, item_table, rel_table,
                                             g_cnt, list, wsL, wsRh, ws_kge, ws_l2);
    ripple_attn<<<BATCH, 256, 0, stream>>>(items, labels, mt, item_table, W,
                                           wsL, wsRh, out, ws_bce);
    ripple_finalize<<<1, 256, 0, stream>>>(ws_bce, ws_kge, ws_l2, out);
}